// Round 1
// baseline (376.680 us; speedup 1.0000x reference)
//
#include <hip/hip_runtime.h>

// TopKMaxPooling: x fp32 [64,256,64,64] -> out fp32 [64,256]
// per row of n=4096: mean of top k=410 values (k = round(0.1*4096)).
// Exact radix-select (4x8-bit passes) on order-preserving uint32 keys,
// one block per row, values resident in registers (16/thread).

#define N_PER_ROW 4096
#define K_SEL 410
#define NROWS (64 * 256)

// monotone float->uint key: ascending uint order == ascending float order
__device__ __forceinline__ unsigned f2k(float f) {
    unsigned u = __float_as_uint(f);
    unsigned mask = ((unsigned)((int)u >> 31)) | 0x80000000u;
    return u ^ mask;
}
__device__ __forceinline__ float k2f(unsigned key) {
    unsigned u = (key & 0x80000000u) ? (key ^ 0x80000000u) : ~key;
    return __uint_as_float(u);
}

__global__ __launch_bounds__(256) void topk_mean_kernel(const float* __restrict__ x,
                                                        float* __restrict__ out) {
    __shared__ unsigned hist[4 * 256];   // per-wave privatized histograms
    __shared__ unsigned sel_bin_s;
    __shared__ unsigned sel_krem_s;
    __shared__ float wsum[4];

    const int tid  = threadIdx.x;
    const int wid  = tid >> 6;
    const int lane = tid & 63;
    const int row  = blockIdx.x;

    const float4* rowp = (const float4*)(x + (size_t)row * N_PER_ROW);

    // coalesced load: 4 float4 per thread, lane-contiguous float4s
    unsigned keys[16];
#pragma unroll
    for (int j = 0; j < 4; ++j) {
        float4 v = rowp[j * 256 + tid];
        keys[4 * j + 0] = f2k(v.x);
        keys[4 * j + 1] = f2k(v.y);
        keys[4 * j + 2] = f2k(v.z);
        keys[4 * j + 3] = f2k(v.w);
    }

    unsigned prefix = 0;   // selected high bits so far
    unsigned krem   = K_SEL;

#pragma unroll
    for (int p = 0; p < 4; ++p) {
        const int shift = 24 - 8 * p;
        // zero histograms (each thread zeroes 4 entries)
#pragma unroll
        for (int i = 0; i < 4; ++i) hist[i * 256 + tid] = 0;
        __syncthreads();

        unsigned* myh = &hist[wid * 256];
#pragma unroll
        for (int j = 0; j < 16; ++j) {
            unsigned key = keys[j];
            // participate if high bits match the selected prefix (all, for p==0)
            bool part = (p == 0) || ((key >> ((shift + 8) & 31)) == prefix);
            if (part) atomicAdd(&myh[(key >> shift) & 255u], 1u);
        }
        __syncthreads();

        // wave 0: suffix-scan 256 bins (4 bins/lane) and pick the bin holding
        // the krem-th largest participant
        if (tid < 64) {
            const int b0 = lane * 4;
            unsigned h0 = hist[b0 + 0] + hist[256 + b0 + 0] + hist[512 + b0 + 0] + hist[768 + b0 + 0];
            unsigned h1 = hist[b0 + 1] + hist[256 + b0 + 1] + hist[512 + b0 + 1] + hist[768 + b0 + 1];
            unsigned h2 = hist[b0 + 2] + hist[256 + b0 + 2] + hist[512 + b0 + 2] + hist[768 + b0 + 2];
            unsigned h3 = hist[b0 + 3] + hist[256 + b0 + 3] + hist[512 + b0 + 3] + hist[768 + b0 + 3];
            // suffix sums within this lane's quad (s_i = sum of bins >= b0+i in quad)
            unsigned s3 = h3;
            unsigned s2 = h2 + s3;
            unsigned s1 = h1 + s2;
            unsigned s0 = h0 + s1;
            unsigned tot = s0;
            // inclusive suffix scan of quad totals across 64 lanes
            unsigned suf = tot;
#pragma unroll
            for (int off = 1; off < 64; off <<= 1) {
                unsigned v = __shfl_down(suf, off, 64);
                if (lane + off < 64) suf += v;
            }
            unsigned above = suf - tot;  // sum of totals for lanes > lane
            unsigned cge0 = s0 + above, cge1 = s1 + above, cge2 = s2 + above, cge3 = s3 + above;
            // unique bin b with cntGT(b) < krem <= cntGE(b)
            if (cge0 >= krem && cge0 - h0 < krem) { sel_bin_s = (unsigned)b0 + 0; sel_krem_s = krem - (cge0 - h0); }
            if (cge1 >= krem && cge1 - h1 < krem) { sel_bin_s = (unsigned)b0 + 1; sel_krem_s = krem - (cge1 - h1); }
            if (cge2 >= krem && cge2 - h2 < krem) { sel_bin_s = (unsigned)b0 + 2; sel_krem_s = krem - (cge2 - h2); }
            if (cge3 >= krem && cge3 - h3 < krem) { sel_bin_s = (unsigned)b0 + 3; sel_krem_s = krem - (cge3 - h3); }
        }
        __syncthreads();
        prefix = (prefix << 8) | sel_bin_s;
        krem   = sel_krem_s;
        // no barrier needed: next write of sel_* is 2 barriers away
    }

    // prefix == exact key of the k-th largest element; krem == how many copies
    // of that exact value are included in the top-k.
    const unsigned T = prefix;
    float s = 0.0f;
#pragma unroll
    for (int j = 0; j < 16; ++j) {
        if (keys[j] > T) s += k2f(keys[j]);
    }
#pragma unroll
    for (int off = 32; off >= 1; off >>= 1) s += __shfl_xor(s, off, 64);
    if (lane == 0) wsum[wid] = s;
    __syncthreads();
    if (tid == 0) {
        float total = wsum[0] + wsum[1] + wsum[2] + wsum[3] + (float)krem * k2f(T);
        out[row] = total * (1.0f / (float)K_SEL);
    }
}

extern "C" void kernel_launch(void* const* d_in, const int* in_sizes, int n_in,
                              void* d_out, int out_size, void* d_ws, size_t ws_size,
                              hipStream_t stream) {
    const float* x = (const float*)d_in[0];
    float* out = (float*)d_out;
    topk_mean_kernel<<<NROWS, 256, 0, stream>>>(x, out);
}

// Round 2
// 354.576 us; speedup vs baseline: 1.0623x; 1.0623x over previous
//
#include <hip/hip_runtime.h>

// TopKMaxPooling: x fp32 [64,256,64,64] -> out fp32 [64,256]
// per row of n=4096: mean of top k=410 values (k = round(0.1*4096)).
// Exact radix-select, 3 passes (11+11+10 bits) on order-preserving uint32
// keys. 2048-bin LDS histogram: fine bins => ~2% max bin occupancy on
// normal data => negligible same-address LDS-atomic serialization
// (vs 256-bin pass0 in R1 which concentrated ~35% into one bin).
// One block per row, values resident in registers (16/thread).

#define N_PER_ROW 4096
#define K_SEL 410
#define NROWS (64 * 256)
#define NBINS 2048

// monotone float->uint key: ascending uint order == ascending float order
__device__ __forceinline__ unsigned f2k(float f) {
    unsigned u = __float_as_uint(f);
    unsigned mask = ((unsigned)((int)u >> 31)) | 0x80000000u;
    return u ^ mask;
}
__device__ __forceinline__ float k2f(unsigned key) {
    unsigned u = (key & 0x80000000u) ? (key ^ 0x80000000u) : ~key;
    return __uint_as_float(u);
}

__global__ __launch_bounds__(256) void topk_mean_kernel(const float* __restrict__ x,
                                                        float* __restrict__ out) {
    __shared__ __align__(16) unsigned cnt[NBINS];  // 8 KB
    __shared__ unsigned wtot[4];
    __shared__ unsigned sel_bin_s;
    __shared__ unsigned sel_krem_s;
    __shared__ float wsum[4];

    const int tid  = threadIdx.x;
    const int wid  = tid >> 6;
    const int lane = tid & 63;
    const int row  = blockIdx.x;

    const float4* rowp = (const float4*)(x + (size_t)row * N_PER_ROW);

    // coalesced load: 4 float4 per thread
    unsigned keys[16];
#pragma unroll
    for (int j = 0; j < 4; ++j) {
        float4 v = rowp[j * 256 + tid];
        keys[4 * j + 0] = f2k(v.x);
        keys[4 * j + 1] = f2k(v.y);
        keys[4 * j + 2] = f2k(v.z);
        keys[4 * j + 3] = f2k(v.w);
    }

    unsigned prefix = 0;   // selected high bits so far (11, then 22 bits)
    unsigned krem   = K_SEL;

#pragma unroll
    for (int p = 0; p < 3; ++p) {
        // ---- zero histogram: 8 words/thread, vectorized ----
        *(uint4*)&cnt[8 * tid]     = make_uint4(0, 0, 0, 0);
        *(uint4*)&cnt[8 * tid + 4] = make_uint4(0, 0, 0, 0);
        __syncthreads();

        // ---- histogram (predicated on prefix match) ----
#pragma unroll
        for (int j = 0; j < 16; ++j) {
            unsigned key = keys[j];
            unsigned b;
            bool part;
            if (p == 0)      { part = true;                       b = key >> 21; }
            else if (p == 1) { part = ((key >> 21) == prefix);    b = (key >> 10) & 0x7FFu; }
            else             { part = ((key >> 10) == prefix);    b = key & 0x3FFu; }
            if (part) atomicAdd(&cnt[b], 1u);
        }
        __syncthreads();

        // ---- suffix scan over 2048 bins, 8 consecutive bins per thread ----
        uint4 c0 = *(const uint4*)&cnt[8 * tid];
        uint4 c1 = *(const uint4*)&cnt[8 * tid + 4];
        unsigned h0 = c0.x, h1 = c0.y, h2 = c0.z, h3 = c0.w;
        unsigned h4 = c1.x, h5 = c1.y, h6 = c1.z, h7 = c1.w;
        unsigned s7 = h7;
        unsigned s6 = h6 + s7, s5 = h5 + s6, s4 = h4 + s5;
        unsigned s3 = h3 + s4, s2 = h2 + s3, s1 = h1 + s2, s0 = h0 + s1;
        unsigned tot = s0;

        // inclusive suffix scan of per-thread totals within wave
        unsigned suf = tot;
#pragma unroll
        for (int off = 1; off < 64; off <<= 1) {
            unsigned v = __shfl_down(suf, off, 64);
            if (lane + off < 64) suf += v;
        }
        if (lane == 0) wtot[wid] = suf;  // wave total
        __syncthreads();

        unsigned above = suf - tot;      // higher threads within wave
        for (int w = wid + 1; w < 4; ++w) above += wtot[w];

        // unique bin b with cntGT(b) < krem <= cntGE(b)
        const unsigned b0 = 8u * (unsigned)tid;
        unsigned cg;
        cg = s0 + above; if (cg >= krem && cg - h0 < krem) { sel_bin_s = b0 + 0; sel_krem_s = krem - (cg - h0); }
        cg = s1 + above; if (cg >= krem && cg - h1 < krem) { sel_bin_s = b0 + 1; sel_krem_s = krem - (cg - h1); }
        cg = s2 + above; if (cg >= krem && cg - h2 < krem) { sel_bin_s = b0 + 2; sel_krem_s = krem - (cg - h2); }
        cg = s3 + above; if (cg >= krem && cg - h3 < krem) { sel_bin_s = b0 + 3; sel_krem_s = krem - (cg - h3); }
        cg = s4 + above; if (cg >= krem && cg - h4 < krem) { sel_bin_s = b0 + 4; sel_krem_s = krem - (cg - h4); }
        cg = s5 + above; if (cg >= krem && cg - h5 < krem) { sel_bin_s = b0 + 5; sel_krem_s = krem - (cg - h5); }
        cg = s6 + above; if (cg >= krem && cg - h6 < krem) { sel_bin_s = b0 + 6; sel_krem_s = krem - (cg - h6); }
        cg = s7 + above; if (cg >= krem && cg - h7 < krem) { sel_bin_s = b0 + 7; sel_krem_s = krem - (cg - h7); }
        __syncthreads();

        prefix = (prefix << (p == 2 ? 10 : 11)) | sel_bin_s;
        krem   = sel_krem_s;
    }

    // prefix == exact 32-bit key of the k-th largest; krem == # copies of it
    // included in the top-k.
    const unsigned T = prefix;
    float s = 0.0f;
#pragma unroll
    for (int j = 0; j < 16; ++j) {
        if (keys[j] > T) s += k2f(keys[j]);
    }
#pragma unroll
    for (int off = 32; off >= 1; off >>= 1) s += __shfl_xor(s, off, 64);
    if (lane == 0) wsum[wid] = s;
    __syncthreads();
    if (tid == 0) {
        float total = wsum[0] + wsum[1] + wsum[2] + wsum[3] + (float)krem * k2f(T);
        out[row] = total * (1.0f / (float)K_SEL);
    }
}

extern "C" void kernel_launch(void* const* d_in, const int* in_sizes, int n_in,
                              void* d_out, int out_size, void* d_ws, size_t ws_size,
                              hipStream_t stream) {
    const float* x = (const float*)d_in[0];
    float* out = (float*)d_out;
    topk_mean_kernel<<<NROWS, 256, 0, stream>>>(x, out);
}